// Round 2
// baseline (700.449 us; speedup 1.0000x reference)
//
#include <hip/hip_runtime.h>
#include <hip/hip_bf16.h>

#define N_  32
#define CI_ 32
#define CO_ 32
#define H_  224
#define W_  224

typedef __attribute__((ext_vector_type(8))) short  bfrag8;   // 8 bf16 in 4 VGPRs
typedef __attribute__((ext_vector_type(4))) float  f32x4;

// Block: 448 threads = 7 waves. Each block: one (n, h, half-row of 112 w),
// all 32 c_out. Wave i owns w-positions [w0+16i, w0+16i+16) x 32 c_out.
// Conv = 9 taps, each tap = one 16x16x32 MFMA per (M-tile, co-tile):
//   out(16 pos x 16 co) += A(16 pos x 32 ci) * B(32 ci x 16 co)
__global__ __launch_bounds__(448) void conv3x3_mfma(
    const float* __restrict__ x, const float* __restrict__ wgt,
    const float* __restrict__ bias, float* __restrict__ out)
{
    // xs[r][w_rel][ci] : rows h-1..h+1, w_rel covers w0-1 .. w0+112 (114 wide)
    // ci padded 32->40 so rows are 80B (16B-aligned b128 reads, uniform banks)
    __shared__ __align__(16) __hip_bfloat16 xs[3][114][40];   // 27,360 B
    // ws[tap][co][ci] : k(ci)-contiguous for B-fragment b128 reads
    __shared__ __align__(16) __hip_bfloat16 ws[9][32][32];    // 18,432 B

    const int tid  = threadIdx.x;
    const int b    = blockIdx.x;
    const int n    = b / 448;
    const int rem  = b % 448;
    const int h    = rem >> 1;
    const int half = rem & 1;
    const int w0   = half * 112;

    // ---- stage weights: wgt[co][ci][kh][kw] -> ws[kh*3+kw][co][ci] (bf16)
    for (int idx = tid; idx < CO_ * CI_ * 9; idx += 448) {
        int co = idx / (CI_ * 9);
        int r  = idx % (CI_ * 9);
        int ci = r / 9;
        int t  = r % 9;
        ws[t][co][ci] = __float2bfloat16(wgt[idx]);
    }

    // ---- stage x tile: 3 rows x 114 w x 32 ci, zero-filled at borders
    for (int idx = tid; idx < 3 * CI_ * 114; idx += 448) {
        int r   = idx / (CI_ * 114);
        int r2  = idx % (CI_ * 114);
        int ci  = r2 / 114;
        int wr  = r2 % 114;
        int hh  = h + r - 1;
        int wwg = w0 - 1 + wr;
        float v = 0.0f;
        if (hh >= 0 && hh < H_ && wwg >= 0 && wwg < W_)
            v = x[((n * CI_ + ci) * H_ + hh) * W_ + wwg];
        xs[r][wr][ci] = __float2bfloat16(v);
    }
    __syncthreads();

    const int wid  = tid >> 6;      // wave id 0..6 -> w-tile
    const int lane = tid & 63;
    const int lm   = lane & 15;     // A: m row / B: co col / D: co col
    const int ko   = lane >> 4;     // k-group (8 ci each)

    // ---- B fragments: lane holds B[ci=8*ko+j][co=lm+16*ct]
    bfrag8 bfr[2][9];
#pragma unroll
    for (int ct = 0; ct < 2; ++ct)
#pragma unroll
        for (int t = 0; t < 9; ++t)
            bfr[ct][t] = *reinterpret_cast<const bfrag8*>(&ws[t][lm + 16 * ct][ko * 8]);

    f32x4 acc[2] = {{0.f, 0.f, 0.f, 0.f}, {0.f, 0.f, 0.f, 0.f}};

    // ---- 9 taps x 2 co-tiles of MFMA. A-frag: lane holds A[m=lm][ci=8*ko+j]
    // x column for tap (kh,kw) at position m: w_rel = 16*wid + m + kw
#pragma unroll
    for (int kh = 0; kh < 3; ++kh) {
#pragma unroll
        for (int kw = 0; kw < 3; ++kw) {
            bfrag8 a = *reinterpret_cast<const bfrag8*>(&xs[kh][16 * wid + lm + kw][ko * 8]);
            acc[0] = __builtin_amdgcn_mfma_f32_16x16x32_bf16(a, bfr[0][kh * 3 + kw], acc[0], 0, 0, 0);
            acc[1] = __builtin_amdgcn_mfma_f32_16x16x32_bf16(a, bfr[1][kh * 3 + kw], acc[1], 0, 0, 0);
        }
    }

    // ---- epilogue: D lane layout row(m)=4*ko+j, col(co)=lm+16*ct
#pragma unroll
    for (int ct = 0; ct < 2; ++ct) {
        int co   = lm + 16 * ct;
        float bv = bias[co];
#pragma unroll
        for (int j = 0; j < 4; ++j) {
            int m = 4 * ko + j;
            int w = w0 + 16 * wid + m;
            out[((n * CO_ + co) * H_ + h) * W_ + w] = acc[ct][j] + bv;
        }
    }
}

extern "C" void kernel_launch(void* const* d_in, const int* in_sizes, int n_in,
                              void* d_out, int out_size, void* d_ws, size_t ws_size,
                              hipStream_t stream) {
    const float* x    = (const float*)d_in[0];
    const float* wgt  = (const float*)d_in[1];
    const float* bias = (const float*)d_in[2];
    float* out        = (float*)d_out;

    // 32 n * 224 h * 2 half-rows = 14336 blocks, 448 threads (7 waves)
    conv3x3_mfma<<<dim3(32 * 224 * 2), dim3(448), 0, stream>>>(x, wgt, bias, out);
}